// Round 1
// baseline (363.821 us; speedup 1.0000x reference)
//
#include <hip/hip_runtime.h>
#include <hip/hip_bf16.h>
#include <stdint.h>

typedef unsigned short u16;
typedef __attribute__((ext_vector_type(8))) short short8;
typedef __attribute__((ext_vector_type(4))) float f32x4;

#define GLOBAL_AS __attribute__((address_space(1)))
#define LDS_AS __attribute__((address_space(3)))

#define BB 4
#define NSEQ 2048
#define DIN 768
#define DOUT 768
#define NH 12
#define HD 64
#define MROWS (BB*NSEQ)   // 8192

static __device__ __forceinline__ u16 f2bf(float f) {
  union { float f; uint32_t u; } v; v.f = f;
  uint32_t r = (v.u + 0x7fffu + ((v.u >> 16) & 1u)) >> 16;
  return (u16)r;
}

// ---------------- convert: fp32 -> bf16 (x) and transposed bf16 weights ----
__global__ void convert_k(const float* __restrict__ x,
                          const float* __restrict__ Wq, const float* __restrict__ Wk,
                          const float* __restrict__ Wv, const float* __restrict__ Wo,
                          u16* __restrict__ xb, u16* __restrict__ WqT,
                          u16* __restrict__ WkT, u16* __restrict__ WvT,
                          u16* __restrict__ WoT) {
  int stride = gridDim.x * blockDim.x;
  int i0 = blockIdx.x * blockDim.x + threadIdx.x;
  for (int i = i0; i < MROWS*DIN; i += stride) xb[i] = f2bf(x[i]);
  for (int i = i0; i < DIN*DOUT; i += stride) {
    int k = i / DOUT, n = i % DOUT;   // read coalesced, write transposed [n][k]
    int o = n * DIN + k;
    WqT[o] = f2bf(Wq[i]);
    WkT[o] = f2bf(Wk[i]);
    WvT[o] = f2bf(Wv[i]);
    WoT[o] = f2bf(Wo[i]);
  }
}

// ---------------- GEMM: C[m][n] = sum_k A[m][k] * Bt[n][k] ------------------
// 128x128 tile, 4 waves (2x2), BK=32, global_load_lds staging.
// MODE 0: out Q bf16 [b][h][n][64], scaled by 0.125
// MODE 1: out K bf16 [b][h][n][64]
// MODE 2: out V^T bf16 [b][h][64][n]  (LDS transpose epilogue)
// MODE 3: out fp32 [m][n] + bias[n]
template<int MODE>
__global__ __launch_bounds__(256) void gemm_k(const u16* __restrict__ A,
                                              const u16* __restrict__ Bt,
                                              u16* __restrict__ outb,
                                              float* __restrict__ outf,
                                              const float* __restrict__ bias) {
  const int K = DIN;
  int m0 = blockIdx.x * 128;
  int n0 = blockIdx.y * 128;
  int tid = threadIdx.x;
  int lane = tid & 63, wid = tid >> 6;
  int wr = wid >> 1, wc = wid & 1;
  int g = lane >> 4, r = lane & 15;

  __shared__ __attribute__((aligned(16))) u16 lA[128*32];
  __shared__ __attribute__((aligned(16))) u16 lB[128*32];

  f32x4 acc[4][4];
#pragma unroll
  for (int i=0;i<4;i++)
#pragma unroll
    for (int j=0;j<4;j++) acc[i][j] = (f32x4){0.f,0.f,0.f,0.f};

  for (int k0 = 0; k0 < K; k0 += 32) {
#pragma unroll
    for (int i=0;i<2;i++) {
      int ch = wid*2 + i;            // 8 chunks of 1024B per tile
      int e = ch*512 + lane*8;       // element index within tile
      int row = e >> 5, col = e & 31;
      __builtin_amdgcn_global_load_lds(
        (GLOBAL_AS void*)(A + (size_t)(m0+row)*K + k0 + col),
        (LDS_AS void*)(&lA[ch*512]), 16, 0, 0);
      __builtin_amdgcn_global_load_lds(
        (GLOBAL_AS void*)(Bt + (size_t)(n0+row)*K + k0 + col),
        (LDS_AS void*)(&lB[ch*512]), 16, 0, 0);
    }
    __syncthreads();
    short8 af[4], bf[4];
#pragma unroll
    for (int f=0; f<4; f++) {
      af[f] = *(const short8*)&lA[(wr*64 + f*16 + r)*32 + g*8];
      bf[f] = *(const short8*)&lB[(wc*64 + f*16 + r)*32 + g*8];
    }
#pragma unroll
    for (int fr=0; fr<4; fr++)
#pragma unroll
      for (int fc=0; fc<4; fc++)
        acc[fr][fc] = __builtin_amdgcn_mfma_f32_16x16x32_bf16(af[fr], bf[fc], acc[fr][fc], 0, 0, 0);
    __syncthreads();
  }

  if constexpr (MODE == 0 || MODE == 1) {
#pragma unroll
    for (int fr=0; fr<4; fr++)
#pragma unroll
      for (int fc=0; fc<4; fc++)
#pragma unroll
        for (int v=0; v<4; v++) {
          int row = m0 + wr*64 + fr*16 + g*4 + v;
          int cc  = n0 + wc*64 + fc*16 + r;
          int b = row >> 11, nn = row & (NSEQ-1);
          float val = acc[fr][fc][v];
          if constexpr (MODE == 0) val *= 0.125f;   // 1/sqrt(64)
          outb[(((size_t)b*NH + (cc>>6))*NSEQ + nn)*HD + (cc&63)] = f2bf(val);
        }
  } else if constexpr (MODE == 2) {
    __shared__ __attribute__((aligned(16))) u16 lC[128*129];
#pragma unroll
    for (int fr=0; fr<4; fr++)
#pragma unroll
      for (int fc=0; fc<4; fc++)
#pragma unroll
        for (int v=0; v<4; v++) {
          int ii = wr*64 + fr*16 + g*4 + v;
          int jj = wc*64 + fc*16 + r;
          lC[ii*129 + jj] = f2bf(acc[fr][fc][v]);
        }
    __syncthreads();
    int b = m0 >> 11;
#pragma unroll 1
    for (int rep=0; rep<64; rep++) {
      int flat = rep*256 + tid;      // 16384 elements
      int jj = flat >> 7, ii = flat & 127;
      int cc = n0 + jj;
      int nn = (m0 + ii) & (NSEQ-1);
      outb[(((size_t)b*NH + (cc>>6))*HD + (cc&63))*NSEQ + nn] = lC[ii*129 + jj];
    }
  } else {
#pragma unroll
    for (int fr=0; fr<4; fr++)
#pragma unroll
      for (int fc=0; fc<4; fc++)
#pragma unroll
        for (int v=0; v<4; v++) {
          int row = m0 + wr*64 + fr*16 + g*4 + v;
          int cc  = n0 + wc*64 + fc*16 + r;
          outf[(size_t)row*DOUT + cc] = acc[fr][fc][v] + bias[cc];
        }
  }
}

// ---------------- flash attention (causal) ---------------------------------
// 1 wave per (bh, 16-row q tile). KV tile = 32. K/V read straight from global
// (per-bh slabs are 256KB -> L2 resident). P bounced through LDS for PV.
__global__ __launch_bounds__(64) void attn_k(const u16* __restrict__ Q,
                                             const u16* __restrict__ Kg,
                                             const u16* __restrict__ Vt,
                                             u16* __restrict__ ctx) {
  int qt = blockIdx.x, bh = blockIdx.y;
  int lane = threadIdx.x;
  int g = lane >> 4, r = lane & 15;
  int q0 = qt * 16;

  const u16* Qp = Q + ((size_t)bh*NSEQ + q0)*HD;
  short8 qf0 = *(const short8*)&Qp[r*HD + g*8];
  short8 qf1 = *(const short8*)&Qp[r*HD + 32 + g*8];

  f32x4 acc[4];
#pragma unroll
  for (int i=0;i<4;i++) acc[i] = (f32x4){0.f,0.f,0.f,0.f};
  float mrow[4] = {-1e30f,-1e30f,-1e30f,-1e30f};
  float lrow[4] = {0.f,0.f,0.f,0.f};

  __shared__ __attribute__((aligned(16))) u16 P[16*40];

  int nkt = (q0 + 47) >> 5;   // ceil((q0+16)/32)
  for (int kt = 0; kt < nkt; kt++) {
    int k0 = kt*32;
    f32x4 s[2];
#pragma unroll
    for (int c=0;c<2;c++) {
      const u16* Kp = Kg + ((size_t)bh*NSEQ + k0 + c*16)*HD;
      short8 kf0 = *(const short8*)&Kp[r*HD + g*8];
      short8 kf1 = *(const short8*)&Kp[r*HD + 32 + g*8];
      f32x4 z = {0.f,0.f,0.f,0.f};
      z = __builtin_amdgcn_mfma_f32_16x16x32_bf16(qf0, kf0, z, 0,0,0);
      z = __builtin_amdgcn_mfma_f32_16x16x32_bf16(qf1, kf1, z, 0,0,0);
      s[c] = z;
    }
    if (kt == nkt-1) {   // only the last tile straddles the diagonal
#pragma unroll
      for (int c=0;c<2;c++)
#pragma unroll
        for (int v=0;v<4;v++)
          if (k0 + c*16 + r > q0 + g*4 + v) s[c][v] = -1e30f;
    }
#pragma unroll
    for (int v=0;v<4;v++) {
      float smax = fmaxf(s[0][v], s[1][v]);
      smax = fmaxf(smax, __shfl_xor(smax, 1));
      smax = fmaxf(smax, __shfl_xor(smax, 2));
      smax = fmaxf(smax, __shfl_xor(smax, 4));
      smax = fmaxf(smax, __shfl_xor(smax, 8));
      float mnew = fmaxf(mrow[v], smax);
      float sc = __expf(mrow[v] - mnew);
      float p0 = __expf(s[0][v] - mnew);
      float p1 = __expf(s[1][v] - mnew);
      float rs = p0 + p1;
      rs += __shfl_xor(rs, 1);
      rs += __shfl_xor(rs, 2);
      rs += __shfl_xor(rs, 4);
      rs += __shfl_xor(rs, 8);
      lrow[v] = lrow[v]*sc + rs;
      mrow[v] = mnew;
#pragma unroll
      for (int db=0; db<4; db++) acc[db][v] *= sc;
      P[(g*4+v)*40 + r]      = f2bf(p0);
      P[(g*4+v)*40 + 16 + r] = f2bf(p1);
    }
    __syncthreads();
    short8 pf = *(const short8*)&P[r*40 + g*8];
#pragma unroll
    for (int db=0; db<4; db++) {
      short8 vf = *(const short8*)&Vt[((size_t)bh*HD + db*16 + r)*NSEQ + k0 + g*8];
      acc[db] = __builtin_amdgcn_mfma_f32_16x16x32_bf16(pf, vf, acc[db], 0,0,0);
    }
    __syncthreads();
  }

  int b = bh / NH, h = bh % NH;
#pragma unroll
  for (int v=0; v<4; v++) {
    float inv = 1.0f / lrow[v];
    int nn = q0 + g*4 + v;
    size_t base = ((size_t)b*NSEQ + nn)*DOUT + h*HD;
#pragma unroll
    for (int db=0; db<4; db++)
      ctx[base + db*16 + r] = f2bf(acc[db][v]*inv);
  }
}

// ---------------------------------------------------------------------------
extern "C" void kernel_launch(void* const* d_in, const int* in_sizes, int n_in,
                              void* d_out, int out_size, void* d_ws, size_t ws_size,
                              hipStream_t stream) {
  const float* x   = (const float*)d_in[0];
  const float* Wq  = (const float*)d_in[1];
  const float* Wk  = (const float*)d_in[2];
  const float* Wv  = (const float*)d_in[3];
  const float* Wo  = (const float*)d_in[4];
  const float* bo  = (const float*)d_in[5];
  float* out = (float*)d_out;

  u16* ws  = (u16*)d_ws;
  u16* xb  = ws;                         // [8192][768]
  u16* WqT = xb  + (size_t)MROWS*DIN;    // [768][768] transposed
  u16* WkT = WqT + (size_t)DIN*DOUT;
  u16* WvT = WkT + (size_t)DIN*DOUT;
  u16* WoT = WvT + (size_t)DIN*DOUT;
  u16* Qg  = WoT + (size_t)DIN*DOUT;     // [b][h][n][64]  (pre-scaled 0.125)
  u16* Kg  = Qg  + (size_t)MROWS*DOUT;   // [b][h][n][64]
  u16* Vt  = Kg  + (size_t)MROWS*DOUT;   // [b][h][64][n]
  u16* ctx = Vt  + (size_t)MROWS*DOUT;   // [b][n][768]

  convert_k<<<2048, 256, 0, stream>>>(x, Wq, Wk, Wv, Wo, xb, WqT, WkT, WvT, WoT);

  dim3 gg(MROWS/128, DOUT/128);
  gemm_k<0><<<gg, 256, 0, stream>>>(xb, WqT, Qg, nullptr, nullptr);
  gemm_k<1><<<gg, 256, 0, stream>>>(xb, WkT, Kg, nullptr, nullptr);
  gemm_k<2><<<gg, 256, 0, stream>>>(xb, WvT, Vt, nullptr, nullptr);

  attn_k<<<dim3(NSEQ/16, BB*NH), 64, 0, stream>>>(Qg, Kg, Vt, ctx);

  gemm_k<3><<<gg, 256, 0, stream>>>(ctx, WoT, nullptr, out, bo);
}

// Round 2
// 226.153 us; speedup vs baseline: 1.6087x; 1.6087x over previous
//
#include <hip/hip_runtime.h>
#include <hip/hip_bf16.h>
#include <stdint.h>

typedef unsigned short u16;
typedef __attribute__((ext_vector_type(8))) short short8;
typedef __attribute__((ext_vector_type(4))) float f32x4;
typedef __attribute__((ext_vector_type(16))) float f32x16;

#define GLOBAL_AS __attribute__((address_space(1)))
#define LDS_AS __attribute__((address_space(3)))

#define BB 4
#define NSEQ 2048
#define DIN 768
#define DOUT 768
#define NH 12
#define HD 64
#define MROWS (BB*NSEQ)   // 8192

static __device__ __forceinline__ u16 f2bf(float f) {
  union { float f; uint32_t u; } v; v.f = f;
  uint32_t r = (v.u + 0x7fffu + ((v.u >> 16) & 1u)) >> 16;
  return (u16)r;
}
static __device__ __forceinline__ uint32_t pack2(float lo, float hi) {
  return ((uint32_t)f2bf(hi) << 16) | (uint32_t)f2bf(lo);
}

// ---------------- convert: fp32 -> bf16 (x) and transposed bf16 weights ----
__global__ void convert_k(const float* __restrict__ x,
                          const float* __restrict__ Wq, const float* __restrict__ Wk,
                          const float* __restrict__ Wv, const float* __restrict__ Wo,
                          u16* __restrict__ xb, u16* __restrict__ WqT,
                          u16* __restrict__ WkT, u16* __restrict__ WvT,
                          u16* __restrict__ WoT) {
  int stride = gridDim.x * blockDim.x;
  int i0 = blockIdx.x * blockDim.x + threadIdx.x;
  for (int i = i0; i < MROWS*DIN; i += stride) xb[i] = f2bf(x[i]);
  for (int i = i0; i < DIN*DOUT; i += stride) {
    int k = i / DOUT, n = i % DOUT;   // read coalesced, write transposed [n][k]
    int o = n * DIN + k;
    WqT[o] = f2bf(Wq[i]);
    WkT[o] = f2bf(Wk[i]);
    WvT[o] = f2bf(Wv[i]);
    WoT[o] = f2bf(Wo[i]);
  }
}

// ---------------- GEMM: C[m][n] = sum_k A[m][k] * Bt[n][k] ------------------
// 128x128 tile, 4 waves (2x2), BK=32, global_load_lds staging.
// MODE 0: out Q bf16 [b][h][n][64], scaled by 0.125*log2(e)  (exp2 softmax)
// MODE 1: out K bf16 [b][h][n][64]
// MODE 2: out V^T bf16 [b][h][64][n]  (LDS transpose epilogue)
// MODE 3: out fp32 [m][n] + bias[n]
template<int MODE>
__global__ __launch_bounds__(256) void gemm_k(const u16* __restrict__ A,
                                              const u16* __restrict__ Bt,
                                              u16* __restrict__ outb,
                                              float* __restrict__ outf,
                                              const float* __restrict__ bias) {
  const int K = DIN;
  int m0 = blockIdx.x * 128;
  int n0 = blockIdx.y * 128;
  int tid = threadIdx.x;
  int lane = tid & 63, wid = tid >> 6;
  int wr = wid >> 1, wc = wid & 1;
  int g = lane >> 4, r = lane & 15;

  __shared__ __attribute__((aligned(16))) u16 lA[128*32];
  __shared__ __attribute__((aligned(16))) u16 lB[128*32];

  f32x4 acc[4][4];
#pragma unroll
  for (int i=0;i<4;i++)
#pragma unroll
    for (int j=0;j<4;j++) acc[i][j] = (f32x4){0.f,0.f,0.f,0.f};

  for (int k0 = 0; k0 < K; k0 += 32) {
#pragma unroll
    for (int i=0;i<2;i++) {
      int ch = wid*2 + i;            // 8 chunks of 1024B per tile
      int e = ch*512 + lane*8;       // element index within tile
      int row = e >> 5, col = e & 31;
      __builtin_amdgcn_global_load_lds(
        (GLOBAL_AS void*)(A + (size_t)(m0+row)*K + k0 + col),
        (LDS_AS void*)(&lA[ch*512]), 16, 0, 0);
      __builtin_amdgcn_global_load_lds(
        (GLOBAL_AS void*)(Bt + (size_t)(n0+row)*K + k0 + col),
        (LDS_AS void*)(&lB[ch*512]), 16, 0, 0);
    }
    __syncthreads();
    short8 af[4], bf[4];
#pragma unroll
    for (int f=0; f<4; f++) {
      af[f] = *(const short8*)&lA[(wr*64 + f*16 + r)*32 + g*8];
      bf[f] = *(const short8*)&lB[(wc*64 + f*16 + r)*32 + g*8];
    }
#pragma unroll
    for (int fr=0; fr<4; fr++)
#pragma unroll
      for (int fc=0; fc<4; fc++)
        acc[fr][fc] = __builtin_amdgcn_mfma_f32_16x16x32_bf16(af[fr], bf[fc], acc[fr][fc], 0, 0, 0);
    __syncthreads();
  }

  if constexpr (MODE == 0 || MODE == 1) {
#pragma unroll
    for (int fr=0; fr<4; fr++)
#pragma unroll
      for (int fc=0; fc<4; fc++)
#pragma unroll
        for (int v=0; v<4; v++) {
          int row = m0 + wr*64 + fr*16 + g*4 + v;
          int cc  = n0 + wc*64 + fc*16 + r;
          int b = row >> 11, nn = row & (NSEQ-1);
          float val = acc[fr][fc][v];
          if constexpr (MODE == 0) val *= 0.18033688f;   // 0.125 * log2(e)
          outb[(((size_t)b*NH + (cc>>6))*NSEQ + nn)*HD + (cc&63)] = f2bf(val);
        }
  } else if constexpr (MODE == 2) {
    __shared__ __attribute__((aligned(16))) u16 lC[128*129];
#pragma unroll
    for (int fr=0; fr<4; fr++)
#pragma unroll
      for (int fc=0; fc<4; fc++)
#pragma unroll
        for (int v=0; v<4; v++) {
          int ii = wr*64 + fr*16 + g*4 + v;
          int jj = wc*64 + fc*16 + r;
          lC[ii*129 + jj] = f2bf(acc[fr][fc][v]);
        }
    __syncthreads();
    int b = m0 >> 11;
#pragma unroll 1
    for (int rep=0; rep<64; rep++) {
      int flat = rep*256 + tid;      // 16384 elements
      int jj = flat >> 7, ii = flat & 127;
      int cc = n0 + jj;
      int nn = (m0 + ii) & (NSEQ-1);
      outb[(((size_t)b*NH + (cc>>6))*HD + (cc&63))*NSEQ + nn] = lC[ii*129 + jj];
    }
  } else {
#pragma unroll
    for (int fr=0; fr<4; fr++)
#pragma unroll
      for (int fc=0; fc<4; fc++)
#pragma unroll
        for (int v=0; v<4; v++) {
          int row = m0 + wr*64 + fr*16 + g*4 + v;
          int cc  = n0 + wc*64 + fc*16 + r;
          outf[(size_t)row*DOUT + cc] = acc[fr][fc][v] + bias[cc];
        }
  }
}

// ---------------- flash attention v2 (causal, swapped-operand 32x32) -------
// 1 wave per 32-row q tile; 4 independent waves per block (strided tile
// assignment for causal balance). KVBLK=64. Zero LDS, zero barriers.
// Swapped QK^T: S^T = mfma(K,Q) -> lane owns one q-row (col=lane&31),
// 16 kv per half-wave. Softmax in-register; P^T built via packed bf16 +
// shfl_xor(32); swapped PV: O^T = mfma(Vt, P^T) so rescale/normalize are
// per-lane scalars.
__global__ __launch_bounds__(256) void attn2_k(const u16* __restrict__ Q,
                                               const u16* __restrict__ Kg,
                                               const u16* __restrict__ Vt,
                                               u16* __restrict__ ctx) {
  int bh = blockIdx.y;
  int lane = threadIdx.x & 63;
  int wid = threadIdx.x >> 6;
  int qt = wid * 16 + blockIdx.x;      // 0..63, strided for load balance
  int q0 = qt * 32;
  int col = lane & 31;
  int hi = lane >> 5;
  int q = q0 + col;

  const u16* Qb = Q  + (size_t)bh * NSEQ * HD;
  const u16* Kb = Kg + (size_t)bh * NSEQ * HD;
  const u16* Vb = Vt + (size_t)bh * HD * NSEQ;

  // Q as B-fragment: col = q (lane&31), k = hi*8+e within each 16-slice
  short8 qf[4];
#pragma unroll
  for (int ksl = 0; ksl < 4; ksl++)
    qf[ksl] = *(const short8*)&Qb[(size_t)q * HD + ksl*16 + hi*8];

  f32x16 od[2];
#pragma unroll
  for (int i=0;i<16;i++) { od[0][i] = 0.f; od[1][i] = 0.f; }
  float m = -1e30f, l = 0.f;

  int nkt = (q0 + 95) >> 6;   // ceil((q0+32)/64)
  for (int kt = 0; kt < nkt; kt++) {
    int k0 = kt * 64;
    f32x16 s[2];
#pragma unroll
    for (int c=0; c<2; c++) {
      f32x16 z;
#pragma unroll
      for (int i=0;i<16;i++) z[i] = 0.f;
#pragma unroll
      for (int ksl=0; ksl<4; ksl++) {
        short8 kf = *(const short8*)&Kb[(size_t)(k0 + c*32 + col) * HD + ksl*16 + hi*8];
        z = __builtin_amdgcn_mfma_f32_32x32x16_bf16(kf, qf[ksl], z, 0, 0, 0);
      }
      s[c] = z;
    }
    if (kt == nkt-1) {   // only the last tile straddles the diagonal
#pragma unroll
      for (int c=0; c<2; c++)
#pragma unroll
        for (int r=0; r<16; r++) {
          int kv = k0 + c*32 + (r&3) + 8*(r>>2) + 4*hi;
          if (kv > q) s[c][r] = -1e30f;
        }
    }
    // ---- online softmax (per-lane q-row) ----
    float pm = s[0][0];
#pragma unroll
    for (int r=1; r<16; r++) pm = fmaxf(pm, s[0][r]);
#pragma unroll
    for (int r=0; r<16; r++) pm = fmaxf(pm, s[1][r]);
    pm = fmaxf(pm, __shfl_xor(pm, 32));
    float mnew = fmaxf(m, pm);
    float sc = __builtin_amdgcn_exp2f(m - mnew);
    float rs = 0.f;
    uint32_t a[2][8];
#pragma unroll
    for (int c=0; c<2; c++)
#pragma unroll
      for (int w=0; w<8; w++) {
        float p0 = __builtin_amdgcn_exp2f(s[c][2*w]   - mnew);
        float p1 = __builtin_amdgcn_exp2f(s[c][2*w+1] - mnew);
        rs += p0 + p1;
        a[c][w] = pack2(p0, p1);
      }
    rs += __shfl_xor(rs, 32);
    l = l * sc + rs;
    m = mnew;
#pragma unroll
    for (int i=0;i<16;i++) { od[0][i] *= sc; od[1][i] *= sc; }

    // ---- PV: O^T += Vt * P^T ----
#pragma unroll
    for (int c=0; c<2; c++) {
      uint32_t b[8];
#pragma unroll
      for (int w=0; w<8; w++) b[w] = (uint32_t)__shfl_xor((int)a[c][w], 32);
      union { uint32_t w[4]; short8 s8; } u0, u1;
      u0.w[0] = hi ? b[2]      : a[c][0];
      u0.w[1] = hi ? b[3]      : a[c][1];
      u0.w[2] = hi ? a[c][2]   : b[0];
      u0.w[3] = hi ? a[c][3]   : b[1];
      u1.w[0] = hi ? b[6]      : a[c][4];
      u1.w[1] = hi ? b[7]      : a[c][5];
      u1.w[2] = hi ? a[c][6]   : b[4];
      u1.w[3] = hi ? a[c][7]   : b[5];
#pragma unroll
      for (int dc=0; dc<2; dc++) {
        short8 vf0 = *(const short8*)&Vb[(size_t)(dc*32 + col) * NSEQ + k0 + c*32 + hi*8];
        od[dc] = __builtin_amdgcn_mfma_f32_32x32x16_bf16(vf0, u0.s8, od[dc], 0, 0, 0);
        short8 vf1 = *(const short8*)&Vb[(size_t)(dc*32 + col) * NSEQ + k0 + c*32 + 16 + hi*8];
        od[dc] = __builtin_amdgcn_mfma_f32_32x32x16_bf16(vf1, u1.s8, od[dc], 0, 0, 0);
      }
    }
  }

  // ---- epilogue: O^T[d][q], lane owns q; d = dc*32 + (r&3)+8*(r>>2)+4*hi
  float inv = 1.0f / l;
  int b = bh / NH, h = bh % NH;
  u16* cp = ctx + ((size_t)b * NSEQ + q) * DOUT + h * HD;
#pragma unroll
  for (int dc=0; dc<2; dc++)
#pragma unroll
    for (int t=0; t<4; t++) {
      int d0 = dc*32 + t*8 + hi*4;
      uint32_t w0 = pack2(od[dc][t*4+0]*inv, od[dc][t*4+1]*inv);
      uint32_t w1 = pack2(od[dc][t*4+2]*inv, od[dc][t*4+3]*inv);
      *(uint32_t*)(cp + d0)     = w0;
      *(uint32_t*)(cp + d0 + 2) = w1;
    }
}

// ---------------------------------------------------------------------------
extern "C" void kernel_launch(void* const* d_in, const int* in_sizes, int n_in,
                              void* d_out, int out_size, void* d_ws, size_t ws_size,
                              hipStream_t stream) {
  const float* x   = (const float*)d_in[0];
  const float* Wq  = (const float*)d_in[1];
  const float* Wk  = (const float*)d_in[2];
  const float* Wv  = (const float*)d_in[3];
  const float* Wo  = (const float*)d_in[4];
  const float* bo  = (const float*)d_in[5];
  float* out = (float*)d_out;

  u16* ws  = (u16*)d_ws;
  u16* xb  = ws;                         // [8192][768]
  u16* WqT = xb  + (size_t)MROWS*DIN;    // [768][768] transposed
  u16* WkT = WqT + (size_t)DIN*DOUT;
  u16* WvT = WkT + (size_t)DIN*DOUT;
  u16* WoT = WvT + (size_t)DIN*DOUT;
  u16* Qg  = WoT + (size_t)DIN*DOUT;     // [b][h][n][64]  (pre-scaled)
  u16* Kg  = Qg  + (size_t)MROWS*DOUT;   // [b][h][n][64]
  u16* Vt  = Kg  + (size_t)MROWS*DOUT;   // [b][h][64][n]
  u16* ctx = Vt  + (size_t)MROWS*DOUT;   // [b][n][768]

  convert_k<<<2048, 256, 0, stream>>>(x, Wq, Wk, Wv, Wo, xb, WqT, WkT, WvT, WoT);

  dim3 gg(MROWS/128, DOUT/128);
  gemm_k<0><<<gg, 256, 0, stream>>>(xb, WqT, Qg, nullptr, nullptr);
  gemm_k<1><<<gg, 256, 0, stream>>>(xb, WkT, Kg, nullptr, nullptr);
  gemm_k<2><<<gg, 256, 0, stream>>>(xb, WvT, Vt, nullptr, nullptr);

  attn2_k<<<dim3(16, BB*NH), 256, 0, stream>>>(Qg, Kg, Vt, ctx);

  gemm_k<3><<<gg, 256, 0, stream>>>(ctx, WoT, nullptr, out, bo);
}

// Round 3
// 204.233 us; speedup vs baseline: 1.7814x; 1.1073x over previous
//
#include <hip/hip_runtime.h>
#include <hip/hip_bf16.h>
#include <stdint.h>

typedef unsigned short u16;
typedef __attribute__((ext_vector_type(8))) short short8;
typedef __attribute__((ext_vector_type(4))) float f32x4;
typedef __attribute__((ext_vector_type(16))) float f32x16;

#define GLOBAL_AS __attribute__((address_space(1)))
#define LDS_AS __attribute__((address_space(3)))

#define BB 4
#define NSEQ 2048
#define DIN 768
#define DOUT 768
#define NH 12
#define HD 64
#define MROWS (BB*NSEQ)   // 8192

static __device__ __forceinline__ u16 f2bf(float f) {
  union { float f; uint32_t u; } v; v.f = f;
  uint32_t r = (v.u + 0x7fffu + ((v.u >> 16) & 1u)) >> 16;
  return (u16)r;
}
static __device__ __forceinline__ uint32_t pack2(float lo, float hi) {
  return ((uint32_t)f2bf(hi) << 16) | (uint32_t)f2bf(lo);
}

// ---------------- convert: fp32 -> bf16 (x) and transposed bf16 weights ----
__global__ void convert_k(const float* __restrict__ x,
                          const float* __restrict__ Wq, const float* __restrict__ Wk,
                          const float* __restrict__ Wv, const float* __restrict__ Wo,
                          u16* __restrict__ xb, u16* __restrict__ WqT,
                          u16* __restrict__ WkT, u16* __restrict__ WvT,
                          u16* __restrict__ WoT) {
  int stride = gridDim.x * blockDim.x;
  int i0 = blockIdx.x * blockDim.x + threadIdx.x;
  for (int i = i0; i < MROWS*DIN; i += stride) xb[i] = f2bf(x[i]);
  for (int i = i0; i < DIN*DOUT; i += stride) {
    int k = i / DOUT, n = i % DOUT;   // read coalesced, write transposed [n][k]
    int o = n * DIN + k;
    WqT[o] = f2bf(Wq[i]);
    WkT[o] = f2bf(Wk[i]);
    WvT[o] = f2bf(Wv[i]);
    WoT[o] = f2bf(Wo[i]);
  }
}

// ---------------- GEMM: C[m][n] = sum_k A[m][k] * Bt[n][k] ------------------
// 128x128 tile, 4 waves (2x2), BK=32, global_load_lds staging.
// MODE 0: out Q bf16 [b][h][n][64], scaled by 0.125*log2(e)  (exp2 softmax)
// MODE 1: out K bf16 [b][h][n][64]
// MODE 2: out V^T bf16 [b][h][64][n]  (LDS transpose epilogue)
// MODE 3: out fp32 [m][n] + bias[n]
template<int MODE>
__global__ __launch_bounds__(256) void gemm_k(const u16* __restrict__ A,
                                              const u16* __restrict__ Bt,
                                              u16* __restrict__ outb,
                                              float* __restrict__ outf,
                                              const float* __restrict__ bias) {
  const int K = DIN;
  int m0 = blockIdx.x * 128;
  int n0 = blockIdx.y * 128;
  int tid = threadIdx.x;
  int lane = tid & 63, wid = tid >> 6;
  int wr = wid >> 1, wc = wid & 1;
  int g = lane >> 4, r = lane & 15;

  __shared__ __attribute__((aligned(16))) u16 lA[128*32];
  __shared__ __attribute__((aligned(16))) u16 lB[128*32];

  f32x4 acc[4][4];
#pragma unroll
  for (int i=0;i<4;i++)
#pragma unroll
    for (int j=0;j<4;j++) acc[i][j] = (f32x4){0.f,0.f,0.f,0.f};

  for (int k0 = 0; k0 < K; k0 += 32) {
#pragma unroll
    for (int i=0;i<2;i++) {
      int ch = wid*2 + i;            // 8 chunks of 1024B per tile
      int e = ch*512 + lane*8;       // element index within tile
      int row = e >> 5, col = e & 31;
      __builtin_amdgcn_global_load_lds(
        (GLOBAL_AS void*)(A + (size_t)(m0+row)*K + k0 + col),
        (LDS_AS void*)(&lA[ch*512]), 16, 0, 0);
      __builtin_amdgcn_global_load_lds(
        (GLOBAL_AS void*)(Bt + (size_t)(n0+row)*K + k0 + col),
        (LDS_AS void*)(&lB[ch*512]), 16, 0, 0);
    }
    __syncthreads();
    short8 af[4], bf[4];
#pragma unroll
    for (int f=0; f<4; f++) {
      af[f] = *(const short8*)&lA[(wr*64 + f*16 + r)*32 + g*8];
      bf[f] = *(const short8*)&lB[(wc*64 + f*16 + r)*32 + g*8];
    }
#pragma unroll
    for (int fr=0; fr<4; fr++)
#pragma unroll
      for (int fc=0; fc<4; fc++)
        acc[fr][fc] = __builtin_amdgcn_mfma_f32_16x16x32_bf16(af[fr], bf[fc], acc[fr][fc], 0, 0, 0);
    __syncthreads();
  }

  if constexpr (MODE == 0 || MODE == 1) {
#pragma unroll
    for (int fr=0; fr<4; fr++)
#pragma unroll
      for (int fc=0; fc<4; fc++)
#pragma unroll
        for (int v=0; v<4; v++) {
          int row = m0 + wr*64 + fr*16 + g*4 + v;
          int cc  = n0 + wc*64 + fc*16 + r;
          int b = row >> 11, nn = row & (NSEQ-1);
          float val = acc[fr][fc][v];
          if constexpr (MODE == 0) val *= 0.18033688f;   // 0.125 * log2(e)
          outb[(((size_t)b*NH + (cc>>6))*NSEQ + nn)*HD + (cc&63)] = f2bf(val);
        }
  } else if constexpr (MODE == 2) {
    __shared__ __attribute__((aligned(16))) u16 lC[128*129];
#pragma unroll
    for (int fr=0; fr<4; fr++)
#pragma unroll
      for (int fc=0; fc<4; fc++)
#pragma unroll
        for (int v=0; v<4; v++) {
          int ii = wr*64 + fr*16 + g*4 + v;
          int jj = wc*64 + fc*16 + r;
          lC[ii*129 + jj] = f2bf(acc[fr][fc][v]);
        }
    __syncthreads();
    int b = m0 >> 11;
#pragma unroll 1
    for (int rep=0; rep<64; rep++) {
      int flat = rep*256 + tid;      // 16384 elements
      int jj = flat >> 7, ii = flat & 127;
      int cc = n0 + jj;
      int nn = (m0 + ii) & (NSEQ-1);
      outb[(((size_t)b*NH + (cc>>6))*HD + (cc&63))*NSEQ + nn] = lC[ii*129 + jj];
    }
  } else {
#pragma unroll
    for (int fr=0; fr<4; fr++)
#pragma unroll
      for (int fc=0; fc<4; fc++)
#pragma unroll
        for (int v=0; v<4; v++) {
          int row = m0 + wr*64 + fr*16 + g*4 + v;
          int cc  = n0 + wc*64 + fc*16 + r;
          outf[(size_t)row*DOUT + cc] = acc[fr][fc][v] + bias[cc];
        }
  }
}

// ---------------- flash attention v3 (causal, LDS-staged, 2-phase) ---------
// Block = 4 waves = 128 consecutive q rows. Per 64-kv tile, the block
// cooperatively stages K (64x64 bf16, 8KB) and V^T (64x64, 8KB) into LDS via
// global_load_lds (1KB/instr, linear dest) with XOR-swizzled SOURCE addresses
// (byte ^= (row&7)<<4 within each 128B row); ds_reads apply the same swizzle.
// Double-buffered: prefetch tile kt+1 issued before computing tile kt; the
// vmcnt(0) drain at the end-of-iter barrier lands after a full compute phase.
// Swapped-operand 32x32 MFMA softmax structure as v2 (zero cross-lane except
// shfl_xor(32) pairs).
__global__ __launch_bounds__(256) void attn3_k(const u16* __restrict__ Q,
                                               const u16* __restrict__ Kg,
                                               const u16* __restrict__ Vt,
                                               u16* __restrict__ ctx) {
  int bh = blockIdx.y;
  int lane = threadIdx.x & 63;
  int w = threadIdx.x >> 6;
  int q0b = (int)(gridDim.x - 1 - blockIdx.x) * 128;   // longest blocks first
  int qw0 = q0b + w * 32;
  int col = lane & 31;
  int hi = lane >> 5;
  int q = qw0 + col;

  const u16* Qb = Q  + (size_t)bh * NSEQ * HD;
  const u16* Kb = Kg + (size_t)bh * NSEQ * HD;
  const u16* Vb = Vt + (size_t)bh * HD * NSEQ;

  __shared__ __attribute__((aligned(16))) u16 lK[2][64*64];
  __shared__ __attribute__((aligned(16))) u16 lV[2][64*64];

  // Q as B-fragment: col = q (lane&31), k = ksl*16 + hi*8 + e
  short8 qf[4];
#pragma unroll
  for (int ksl = 0; ksl < 4; ksl++)
    qf[ksl] = *(const short8*)&Qb[(size_t)q * HD + ksl*16 + hi*8];

  f32x16 od[2];
#pragma unroll
  for (int i=0;i<16;i++) { od[0][i] = 0.f; od[1][i] = 0.f; }
  float m = -1e30f, l = 0.f;

  // ---- staging: linear LDS dest, swizzled global source (rule #21) ----
  auto stage = [&](int buf, int k0) {
#pragma unroll
    for (int i=0;i<2;i++) {
      int cb = (w*2+i) * 1024;          // byte base within 8KB tile
      int d  = cb + lane*16;            // this lane's linear LDS dest byte
      int row = d >> 7;                 // 128B rows
      int src = (d & 127) ^ ((row & 7) << 4);
      __builtin_amdgcn_global_load_lds(
        (GLOBAL_AS void*)((const char*)Kb + (size_t)(k0+row)*128 + src),
        (LDS_AS void*)((char*)&lK[buf][0] + cb), 16, 0, 0);
      __builtin_amdgcn_global_load_lds(
        (GLOBAL_AS void*)((const char*)Vb + (size_t)row*(NSEQ*2) + (size_t)k0*2 + src),
        (LDS_AS void*)((char*)&lV[buf][0] + cb), 16, 0, 0);
    }
  };

  int nkt = q0b/64 + 2;                  // tiles for the whole block
  int sw = (col & 7) << 4;               // read-side swizzle (row&7 == col&7)

  stage(0, 0);
  __syncthreads();

  int buf = 0;
  for (int kt = 0; kt < nkt; kt++) {
    int k0 = kt * 64;
    if (kt + 1 < nkt) stage(buf ^ 1, k0 + 64);

    if (k0 < qw0 + 32) {                 // this wave has live kv in the tile
      const char* Kt = (const char*)&lK[buf][0];
      const char* Vtile = (const char*)&lV[buf][0];
      f32x16 s[2];
#pragma unroll
      for (int c=0; c<2; c++) {
        f32x16 z;
#pragma unroll
        for (int i=0;i<16;i++) z[i] = 0.f;
#pragma unroll
        for (int ksl=0; ksl<4; ksl++) {
          short8 kf = *(const short8*)(Kt + (c*32+col)*128 + ((ksl*32 + hi*16) ^ sw));
          z = __builtin_amdgcn_mfma_f32_32x32x16_bf16(kf, qf[ksl], z, 0, 0, 0);
        }
        s[c] = z;
      }
      if (k0 + 63 > qw0) {               // tile straddles some lane's diagonal
#pragma unroll
        for (int c=0; c<2; c++)
#pragma unroll
          for (int r=0; r<16; r++) {
            int kv = k0 + c*32 + (r&3) + 8*(r>>2) + 4*hi;
            if (kv > q) s[c][r] = -1e30f;
          }
      }
      // ---- online softmax (per-lane q-row) ----
      float pm = s[0][0];
#pragma unroll
      for (int r=1; r<16; r++) pm = fmaxf(pm, s[0][r]);
#pragma unroll
      for (int r=0; r<16; r++) pm = fmaxf(pm, s[1][r]);
      pm = fmaxf(pm, __shfl_xor(pm, 32));
      float mnew = fmaxf(m, pm);
      float sc = __builtin_amdgcn_exp2f(m - mnew);
      float rs = 0.f;
      uint32_t a[2][8];
#pragma unroll
      for (int c=0; c<2; c++)
#pragma unroll
        for (int ww=0; ww<8; ww++) {
          float p0 = __builtin_amdgcn_exp2f(s[c][2*ww]   - mnew);
          float p1 = __builtin_amdgcn_exp2f(s[c][2*ww+1] - mnew);
          rs += p0 + p1;
          a[c][ww] = pack2(p0, p1);
        }
      rs += __shfl_xor(rs, 32);
      l = l * sc + rs;
      m = mnew;
#pragma unroll
      for (int i=0;i<16;i++) { od[0][i] *= sc; od[1][i] *= sc; }

      // ---- PV: O^T += Vt * P^T ----
#pragma unroll
      for (int c=0; c<2; c++) {
        uint32_t b[8];
#pragma unroll
        for (int ww=0; ww<8; ww++) b[ww] = (uint32_t)__shfl_xor((int)a[c][ww], 32);
        union { uint32_t wdat[4]; short8 s8; } u0, u1;
        u0.wdat[0] = hi ? b[2]      : a[c][0];
        u0.wdat[1] = hi ? b[3]      : a[c][1];
        u0.wdat[2] = hi ? a[c][2]   : b[0];
        u0.wdat[3] = hi ? a[c][3]   : b[1];
        u1.wdat[0] = hi ? b[6]      : a[c][4];
        u1.wdat[1] = hi ? b[7]      : a[c][5];
        u1.wdat[2] = hi ? a[c][6]   : b[4];
        u1.wdat[3] = hi ? a[c][7]   : b[5];
#pragma unroll
        for (int dc=0; dc<2; dc++) {
          short8 vf0 = *(const short8*)(Vtile + (dc*32+col)*128 + ((c*64 + hi*16) ^ sw));
          od[dc] = __builtin_amdgcn_mfma_f32_32x32x16_bf16(vf0, u0.s8, od[dc], 0, 0, 0);
          short8 vf1 = *(const short8*)(Vtile + (dc*32+col)*128 + ((c*64 + 32 + hi*16) ^ sw));
          od[dc] = __builtin_amdgcn_mfma_f32_32x32x16_bf16(vf1, u1.s8, od[dc], 0, 0, 0);
        }
      }
    }
    __syncthreads();   // drains stage loads; guards buf reuse
    buf ^= 1;
  }

  // ---- epilogue: O^T[d][q], lane owns q; d = dc*32 + (t&3)+8*(t>>2)+4*hi
  float inv = 1.0f / l;
  int b = bh / NH, h = bh % NH;
  u16* cp = ctx + ((size_t)b * NSEQ + q) * DOUT + h * HD;
#pragma unroll
  for (int dc=0; dc<2; dc++)
#pragma unroll
    for (int t=0; t<4; t++) {
      int d0 = dc*32 + t*8 + hi*4;
      uint32_t w0 = pack2(od[dc][t*4+0]*inv, od[dc][t*4+1]*inv);
      uint32_t w1 = pack2(od[dc][t*4+2]*inv, od[dc][t*4+3]*inv);
      *(uint32_t*)(cp + d0)     = w0;
      *(uint32_t*)(cp + d0 + 2) = w1;
    }
}

// ---------------------------------------------------------------------------
extern "C" void kernel_launch(void* const* d_in, const int* in_sizes, int n_in,
                              void* d_out, int out_size, void* d_ws, size_t ws_size,
                              hipStream_t stream) {
  const float* x   = (const float*)d_in[0];
  const float* Wq  = (const float*)d_in[1];
  const float* Wk  = (const float*)d_in[2];
  const float* Wv  = (const float*)d_in[3];
  const float* Wo  = (const float*)d_in[4];
  const float* bo  = (const float*)d_in[5];
  float* out = (float*)d_out;

  u16* ws  = (u16*)d_ws;
  u16* xb  = ws;                         // [8192][768]
  u16* WqT = xb  + (size_t)MROWS*DIN;    // [768][768] transposed
  u16* WkT = WqT + (size_t)DIN*DOUT;
  u16* WvT = WkT + (size_t)DIN*DOUT;
  u16* WoT = WvT + (size_t)DIN*DOUT;
  u16* Qg  = WoT + (size_t)DIN*DOUT;     // [b][h][n][64]  (pre-scaled)
  u16* Kg  = Qg  + (size_t)MROWS*DOUT;   // [b][h][n][64]
  u16* Vt  = Kg  + (size_t)MROWS*DOUT;   // [b][h][64][n]
  u16* ctx = Vt  + (size_t)MROWS*DOUT;   // [b][n][768]

  convert_k<<<2048, 256, 0, stream>>>(x, Wq, Wk, Wv, Wo, xb, WqT, WkT, WvT, WoT);

  dim3 gg(MROWS/128, DOUT/128);
  gemm_k<0><<<gg, 256, 0, stream>>>(xb, WqT, Qg, nullptr, nullptr);
  gemm_k<1><<<gg, 256, 0, stream>>>(xb, WkT, Kg, nullptr, nullptr);
  gemm_k<2><<<gg, 256, 0, stream>>>(xb, WvT, Vt, nullptr, nullptr);

  attn3_k<<<dim3(16, BB*NH), 256, 0, stream>>>(Qg, Kg, Vt, ctx);

  gemm_k<3><<<gg, 256, 0, stream>>>(ctx, WoT, nullptr, out, bo);
}

// Round 4
// 198.524 us; speedup vs baseline: 1.8326x; 1.0288x over previous
//
#include <hip/hip_runtime.h>
#include <hip/hip_bf16.h>
#include <stdint.h>

typedef unsigned short u16;
typedef __attribute__((ext_vector_type(8))) short short8;
typedef __attribute__((ext_vector_type(4))) float f32x4;
typedef __attribute__((ext_vector_type(16))) float f32x16;

#define GLOBAL_AS __attribute__((address_space(1)))
#define LDS_AS __attribute__((address_space(3)))

#define BB 4
#define NSEQ 2048
#define DIN 768
#define DOUT 768
#define NH 12
#define HD 64
#define MROWS (BB*NSEQ)   // 8192

static __device__ __forceinline__ u16 f2bf(float f) {
  union { float f; uint32_t u; } v; v.f = f;
  uint32_t r = (v.u + 0x7fffu + ((v.u >> 16) & 1u)) >> 16;
  return (u16)r;
}
// hardware cvt path (compiler fuses pairs into v_cvt_pk_bf16_f32)
static __device__ __forceinline__ uint32_t pack2b(float lo, float hi) {
  union { __hip_bfloat162 h; uint32_t u; } cv;
  cv.h.x = __float2bfloat16(lo);
  cv.h.y = __float2bfloat16(hi);
  return cv.u;
}

// ---------------- convert: fp32 -> bf16 (x) and transposed bf16 weights ----
__global__ void convert_k(const float* __restrict__ x,
                          const float* __restrict__ Wq, const float* __restrict__ Wk,
                          const float* __restrict__ Wv, const float* __restrict__ Wo,
                          u16* __restrict__ xb, u16* __restrict__ WqT,
                          u16* __restrict__ WkT, u16* __restrict__ WvT,
                          u16* __restrict__ WoT) {
  int stride = gridDim.x * blockDim.x;
  int i0 = blockIdx.x * blockDim.x + threadIdx.x;
  for (int i = i0; i < MROWS*DIN; i += stride) xb[i] = f2bf(x[i]);
  for (int i = i0; i < DIN*DOUT; i += stride) {
    int k = i / DOUT, n = i % DOUT;   // read coalesced, write transposed [n][k]
    int o = n * DIN + k;
    WqT[o] = f2bf(Wq[i]);
    WkT[o] = f2bf(Wk[i]);
    WvT[o] = f2bf(Wv[i]);
    WoT[o] = f2bf(Wo[i]);
  }
}

// ---------------- GEMM: C[m][n] = sum_k A[m][k] * Bt[n][k] ------------------
// 128x128 tile, 4 waves (2x2), BK=32, global_load_lds staging.
// MODE 0: out Q bf16 [b][h][n][64], scaled by 0.125*log2(e)  (exp2 softmax)
// MODE 1: out K bf16 [b][h][n][64]
// MODE 2: out V^T bf16 [b][h][64][n]  (LDS transpose epilogue)
// MODE 3: out fp32 [m][n] + bias[n]
template<int MODE>
__global__ __launch_bounds__(256) void gemm_k(const u16* __restrict__ A,
                                              const u16* __restrict__ Bt,
                                              u16* __restrict__ outb,
                                              float* __restrict__ outf,
                                              const float* __restrict__ bias) {
  const int K = DIN;
  int m0 = blockIdx.x * 128;
  int n0 = blockIdx.y * 128;
  int tid = threadIdx.x;
  int lane = tid & 63, wid = tid >> 6;
  int wr = wid >> 1, wc = wid & 1;
  int g = lane >> 4, r = lane & 15;

  __shared__ __attribute__((aligned(16))) u16 lA[128*32];
  __shared__ __attribute__((aligned(16))) u16 lB[128*32];

  f32x4 acc[4][4];
#pragma unroll
  for (int i=0;i<4;i++)
#pragma unroll
    for (int j=0;j<4;j++) acc[i][j] = (f32x4){0.f,0.f,0.f,0.f};

  for (int k0 = 0; k0 < K; k0 += 32) {
#pragma unroll
    for (int i=0;i<2;i++) {
      int ch = wid*2 + i;            // 8 chunks of 1024B per tile
      int e = ch*512 + lane*8;       // element index within tile
      int row = e >> 5, col = e & 31;
      __builtin_amdgcn_global_load_lds(
        (GLOBAL_AS void*)(A + (size_t)(m0+row)*K + k0 + col),
        (LDS_AS void*)(&lA[ch*512]), 16, 0, 0);
      __builtin_amdgcn_global_load_lds(
        (GLOBAL_AS void*)(Bt + (size_t)(n0+row)*K + k0 + col),
        (LDS_AS void*)(&lB[ch*512]), 16, 0, 0);
    }
    __syncthreads();
    short8 af[4], bf[4];
#pragma unroll
    for (int f=0; f<4; f++) {
      af[f] = *(const short8*)&lA[(wr*64 + f*16 + r)*32 + g*8];
      bf[f] = *(const short8*)&lB[(wc*64 + f*16 + r)*32 + g*8];
    }
#pragma unroll
    for (int fr=0; fr<4; fr++)
#pragma unroll
      for (int fc=0; fc<4; fc++)
        acc[fr][fc] = __builtin_amdgcn_mfma_f32_16x16x32_bf16(af[fr], bf[fc], acc[fr][fc], 0, 0, 0);
    __syncthreads();
  }

  if constexpr (MODE == 0 || MODE == 1) {
#pragma unroll
    for (int fr=0; fr<4; fr++)
#pragma unroll
      for (int fc=0; fc<4; fc++)
#pragma unroll
        for (int v=0; v<4; v++) {
          int row = m0 + wr*64 + fr*16 + g*4 + v;
          int cc  = n0 + wc*64 + fc*16 + r;
          int b = row >> 11, nn = row & (NSEQ-1);
          float val = acc[fr][fc][v];
          if constexpr (MODE == 0) val *= 0.18033688f;   // 0.125 * log2(e)
          outb[(((size_t)b*NH + (cc>>6))*NSEQ + nn)*HD + (cc&63)] = f2bf(val);
        }
  } else if constexpr (MODE == 2) {
    __shared__ __attribute__((aligned(16))) u16 lC[128*129];
#pragma unroll
    for (int fr=0; fr<4; fr++)
#pragma unroll
      for (int fc=0; fc<4; fc++)
#pragma unroll
        for (int v=0; v<4; v++) {
          int ii = wr*64 + fr*16 + g*4 + v;
          int jj = wc*64 + fc*16 + r;
          lC[ii*129 + jj] = f2bf(acc[fr][fc][v]);
        }
    __syncthreads();
    int b = m0 >> 11;
#pragma unroll 1
    for (int rep=0; rep<64; rep++) {
      int flat = rep*256 + tid;      // 16384 elements
      int jj = flat >> 7, ii = flat & 127;
      int cc = n0 + jj;
      int nn = (m0 + ii) & (NSEQ-1);
      outb[(((size_t)b*NH + (cc>>6))*HD + (cc&63))*NSEQ + nn] = lC[ii*129 + jj];
    }
  } else {
#pragma unroll
    for (int fr=0; fr<4; fr++)
#pragma unroll
      for (int fc=0; fc<4; fc++)
#pragma unroll
        for (int v=0; v<4; v++) {
          int row = m0 + wr*64 + fr*16 + g*4 + v;
          int cc  = n0 + wc*64 + fc*16 + r;
          outf[(size_t)row*DOUT + cc] = acc[fr][fc][v] + bias[cc];
        }
  }
}

// ---------------- flash attention v4 ---------------------------------------
// Uniform-work blocks: block = 4 waves = 2 wave-pairs over a 64-row q chunk;
// two sequential phases handle chunk c and mirror chunk 31-c (33 staged
// kv-tiles per block, exactly uniform). Within a pair, the 2 waves cover the
// SAME 32 q rows but split kv tiles by parity (private m/l/O, merged through
// LDS once per phase) -> 6144 waves, all resident, balanced.
// Per tile: block stages K(8KB)+V^T(8KB) into LDS (global_load_lds, linear
// dest, XOR-swizzled source; reads re-apply swizzle). Softmax: swapped-QK^T
// in-register, defer-rescale (THR=8 log2), hw cvt_pk bf16 packing.
__global__ __launch_bounds__(256, 2) void attn4_k(const u16* __restrict__ Q,
                                                  const u16* __restrict__ Kg,
                                                  const u16* __restrict__ Vt,
                                                  u16* __restrict__ ctx) {
  int cx = blockIdx.x;                 // 0..15 chunk-pair
  int bh = blockIdx.y;
  int lane = threadIdx.x & 63;
  int w = threadIdx.x >> 6;            // 0..3
  int p = w >> 1;                      // pair id (q sub-chunk)
  int par = w & 1;                     // kv tile parity
  int col = lane & 31;
  int hi = lane >> 5;
  int sw = (col & 7) << 4;             // read-side swizzle

  const u16* Qb = Q  + (size_t)bh * NSEQ * HD;
  const u16* Kb = Kg + (size_t)bh * NSEQ * HD;
  const u16* Vb = Vt + (size_t)bh * HD * NSEQ;

  __shared__ __attribute__((aligned(16))) char smem[2][16384];  // {K:0..8K, V:8K..16K} x dbuf

  // stage one 64-kv tile (K 8KB + V^T 8KB) cooperatively (4 waves)
  auto stage = [&](int buf, int k0) {
#pragma unroll
    for (int i=0;i<2;i++) {
      int cb = (w*2+i) * 1024;
      int d  = cb + lane*16;
      int row = d >> 7;
      int src = (d & 127) ^ ((row & 7) << 4);
      __builtin_amdgcn_global_load_lds(
        (GLOBAL_AS void*)((const char*)Kb + (size_t)(k0+row)*128 + src),
        (LDS_AS void*)(&smem[buf][cb]), 16, 0, 0);
      __builtin_amdgcn_global_load_lds(
        (GLOBAL_AS void*)((const char*)Vb + (size_t)row*(NSEQ*2) + (size_t)k0*2 + src),
        (LDS_AS void*)(&smem[buf][8192+cb]), 16, 0, 0);
    }
  };

#pragma unroll 1
  for (int ph = 0; ph < 2; ph++) {
    int chunk = ph ? (31 - cx) : cx;
    int nkt = chunk + 1;
    int qw0 = chunk*64 + p*32;
    int q = qw0 + col;

    short8 qf[4];
#pragma unroll
    for (int ksl = 0; ksl < 4; ksl++)
      qf[ksl] = *(const short8*)&Qb[(size_t)q * HD + ksl*16 + hi*8];

    f32x16 od[2];
#pragma unroll
    for (int i=0;i<16;i++) { od[0][i] = 0.f; od[1][i] = 0.f; }
    float m = -1e30f, l = 0.f;

    stage(0, 0);
    __syncthreads();
    int buf = 0;
#pragma unroll 1
    for (int t = 0; t < nkt; t++) {
      if (t + 1 < nkt) stage(buf ^ 1, (t+1)*64);

      if ((t & 1) == par) {
        int k0 = t * 64;
        const char* Kt = &smem[buf][0];
        const char* Vtile = &smem[buf][8192];
        f32x16 s[2];
#pragma unroll
        for (int c=0; c<2; c++) {
          f32x16 z;
#pragma unroll
          for (int i=0;i<16;i++) z[i] = 0.f;
#pragma unroll
          for (int ksl=0; ksl<4; ksl++) {
            short8 kf = *(const short8*)(Kt + (c*32+col)*128 + ((ksl*32 + hi*16) ^ sw));
            z = __builtin_amdgcn_mfma_f32_32x32x16_bf16(kf, qf[ksl], z, 0, 0, 0);
          }
          s[c] = z;
        }
        if (t == chunk) {              // diagonal tile: causal mask
#pragma unroll
          for (int c=0; c<2; c++)
#pragma unroll
            for (int r=0; r<16; r++) {
              int kv = k0 + c*32 + (r&3) + 8*(r>>2) + 4*hi;
              if (kv > q) s[c][r] = -1e30f;
            }
        }
        // ---- tree max + defer-rescale ----
        float u8[16];
#pragma unroll
        for (int r=0; r<16; r++) u8[r] = fmaxf(s[0][r], s[1][r]);
#pragma unroll
        for (int r=0; r<8; r++) u8[r] = fmaxf(u8[r], u8[r+8]);
#pragma unroll
        for (int r=0; r<4; r++) u8[r] = fmaxf(u8[r], u8[r+4]);
        float pm = fmaxf(fmaxf(u8[0], u8[1]), fmaxf(u8[2], u8[3]));
        pm = fmaxf(pm, __shfl_xor(pm, 32));
        if (!__all(pm <= m + 8.0f)) {
          float mnew = fmaxf(m, pm);
          float sc = __builtin_amdgcn_exp2f(m - mnew);
          l *= sc;
#pragma unroll
          for (int i=0;i<16;i++) { od[0][i] *= sc; od[1][i] *= sc; }
          m = mnew;
        }
        float rs0 = 0.f, rs1 = 0.f;
        uint32_t a[2][8];
#pragma unroll
        for (int c=0; c<2; c++)
#pragma unroll
          for (int ww=0; ww<8; ww++) {
            float p0 = __builtin_amdgcn_exp2f(s[c][2*ww]   - m);
            float p1 = __builtin_amdgcn_exp2f(s[c][2*ww+1] - m);
            if (c) rs1 += p0 + p1; else rs0 += p0 + p1;
            a[c][ww] = pack2b(p0, p1);
          }
        float rs = rs0 + rs1;
        rs += __shfl_xor(rs, 32);
        l += rs;

        // ---- PV: O^T += Vt * P^T ----
#pragma unroll
        for (int c=0; c<2; c++) {
          uint32_t b[8];
#pragma unroll
          for (int ww=0; ww<8; ww++) b[ww] = (uint32_t)__shfl_xor((int)a[c][ww], 32);
          union { uint32_t wdat[4]; short8 s8; } u0, u1;
          u0.wdat[0] = hi ? b[2]      : a[c][0];
          u0.wdat[1] = hi ? b[3]      : a[c][1];
          u0.wdat[2] = hi ? a[c][2]   : b[0];
          u0.wdat[3] = hi ? a[c][3]   : b[1];
          u1.wdat[0] = hi ? b[6]      : a[c][4];
          u1.wdat[1] = hi ? b[7]      : a[c][5];
          u1.wdat[2] = hi ? a[c][6]   : b[4];
          u1.wdat[3] = hi ? a[c][7]   : b[5];
#pragma unroll
          for (int dc=0; dc<2; dc++) {
            short8 vf0 = *(const short8*)(Vtile + (dc*32+col)*128 + ((c*64 + hi*16) ^ sw));
            od[dc] = __builtin_amdgcn_mfma_f32_32x32x16_bf16(vf0, u0.s8, od[dc], 0, 0, 0);
            short8 vf1 = *(const short8*)(Vtile + (dc*32+col)*128 + ((c*64 + 32 + hi*16) ^ sw));
            od[dc] = __builtin_amdgcn_mfma_f32_32x32x16_bf16(vf1, u1.s8, od[dc], 0, 0, 0);
          }
        }
      }
      __syncthreads();
      buf ^= 1;
    }

    // ---- pair merge through LDS (staging region is free now) ----
    float* mg = (float*)&smem[0][0] + p * (34*64);
    if (par) {
#pragma unroll
      for (int dc=0; dc<2; dc++)
#pragma unroll
        for (int j=0; j<16; j++) mg[(dc*16+j)*64 + lane] = od[dc][j];
      mg[32*64 + lane] = m;
      mg[33*64 + lane] = l;
    }
    __syncthreads();
    if (!par) {
      float mB = mg[32*64 + lane], lB = mg[33*64 + lane];
      float mM = fmaxf(m, mB);
      float ea = __builtin_amdgcn_exp2f(m - mM);
      float eb = __builtin_amdgcn_exp2f(mB - mM);
      float inv = 1.0f / (l*ea + lB*eb);
      float fa = ea * inv, fb = eb * inv;
      int b = bh / NH, h = bh % NH;
      u16* cp = ctx + ((size_t)b * NSEQ + q) * DOUT + h * HD;
#pragma unroll
      for (int dc=0; dc<2; dc++)
#pragma unroll
        for (int t4=0; t4<4; t4++) {
          int d0 = dc*32 + t4*8 + hi*4;
          float v0 = od[dc][t4*4+0]*fa + mg[(dc*16+t4*4+0)*64 + lane]*fb;
          float v1 = od[dc][t4*4+1]*fa + mg[(dc*16+t4*4+1)*64 + lane]*fb;
          float v2 = od[dc][t4*4+2]*fa + mg[(dc*16+t4*4+2)*64 + lane]*fb;
          float v3 = od[dc][t4*4+3]*fa + mg[(dc*16+t4*4+3)*64 + lane]*fb;
          *(uint32_t*)(cp + d0)     = pack2b(v0, v1);
          *(uint32_t*)(cp + d0 + 2) = pack2b(v2, v3);
        }
    }
    __syncthreads();   // protect merge region before next phase's staging
  }
}

// ---------------------------------------------------------------------------
extern "C" void kernel_launch(void* const* d_in, const int* in_sizes, int n_in,
                              void* d_out, int out_size, void* d_ws, size_t ws_size,
                              hipStream_t stream) {
  const float* x   = (const float*)d_in[0];
  const float* Wq  = (const float*)d_in[1];
  const float* Wk  = (const float*)d_in[2];
  const float* Wv  = (const float*)d_in[3];
  const float* Wo  = (const float*)d_in[4];
  const float* bo  = (const float*)d_in[5];
  float* out = (float*)d_out;

  u16* ws  = (u16*)d_ws;
  u16* xb  = ws;                         // [8192][768]
  u16* WqT = xb  + (size_t)MROWS*DIN;    // [768][768] transposed
  u16* WkT = WqT + (size_t)DIN*DOUT;
  u16* WvT = WkT + (size_t)DIN*DOUT;
  u16* WoT = WvT + (size_t)DIN*DOUT;
  u16* Qg  = WoT + (size_t)DIN*DOUT;     // [b][h][n][64]  (pre-scaled)
  u16* Kg  = Qg  + (size_t)MROWS*DOUT;   // [b][h][n][64]
  u16* Vt  = Kg  + (size_t)MROWS*DOUT;   // [b][h][64][n]
  u16* ctx = Vt  + (size_t)MROWS*DOUT;   // [b][n][768]

  convert_k<<<2048, 256, 0, stream>>>(x, Wq, Wk, Wv, Wo, xb, WqT, WkT, WvT, WoT);

  dim3 gg(MROWS/128, DOUT/128);
  gemm_k<0><<<gg, 256, 0, stream>>>(xb, WqT, Qg, nullptr, nullptr);
  gemm_k<1><<<gg, 256, 0, stream>>>(xb, WkT, Kg, nullptr, nullptr);
  gemm_k<2><<<gg, 256, 0, stream>>>(xb, WvT, Vt, nullptr, nullptr);

  attn4_k<<<dim3(16, BB*NH), 256, 0, stream>>>(Qg, Kg, Vt, ctx);

  gemm_k<3><<<gg, 256, 0, stream>>>(ctx, WoT, nullptr, out, bo);
}

// Round 5
// 159.941 us; speedup vs baseline: 2.2747x; 1.2412x over previous
//
#include <hip/hip_runtime.h>
#include <hip/hip_bf16.h>
#include <stdint.h>

typedef unsigned short u16;
typedef __attribute__((ext_vector_type(8))) short short8;
typedef __attribute__((ext_vector_type(4))) float f32x4;
typedef __attribute__((ext_vector_type(16))) float f32x16;

#define GLOBAL_AS __attribute__((address_space(1)))
#define LDS_AS __attribute__((address_space(3)))

#define BB 4
#define NSEQ 2048
#define DIN 768
#define DOUT 768
#define NH 12
#define HD 64
#define MROWS (BB*NSEQ)   // 8192

static __device__ __forceinline__ u16 f2bf(float f) {
  union { float f; uint32_t u; } v; v.f = f;
  uint32_t r = (v.u + 0x7fffu + ((v.u >> 16) & 1u)) >> 16;
  return (u16)r;
}
// hardware cvt path (compiler fuses pairs into v_cvt_pk_bf16_f32)
static __device__ __forceinline__ uint32_t pack2b(float lo, float hi) {
  union { __hip_bfloat162 h; uint32_t u; } cv;
  cv.h.x = __float2bfloat16(lo);
  cv.h.y = __float2bfloat16(hi);
  return cv.u;
}

// ---------------- convert: fp32 -> bf16 (x) and transposed bf16 weights ----
__global__ void convert_k(const float* __restrict__ x,
                          const float* __restrict__ Wq, const float* __restrict__ Wk,
                          const float* __restrict__ Wv, const float* __restrict__ Wo,
                          u16* __restrict__ xb, u16* __restrict__ WqT,
                          u16* __restrict__ WkT, u16* __restrict__ WvT,
                          u16* __restrict__ WoT) {
  int stride = gridDim.x * blockDim.x;
  int i0 = blockIdx.x * blockDim.x + threadIdx.x;
  for (int i = i0; i < MROWS*DIN; i += stride) xb[i] = f2bf(x[i]);
  for (int i = i0; i < DIN*DOUT; i += stride) {
    int k = i / DOUT, n = i % DOUT;   // read coalesced, write transposed [n][k]
    int o = n * DIN + k;
    WqT[o] = f2bf(Wq[i]);
    WkT[o] = f2bf(Wk[i]);
    WvT[o] = f2bf(Wv[i]);
    WoT[o] = f2bf(Wo[i]);
  }
}

// ---------------- GEMM: C[m][n] = sum_k A[m][k] * Bt[n][k] ------------------
// 128x128 tile, 4 waves (2x2), BK=32, global_load_lds staging.
// MODE 0: out Q bf16 [b][h][n][64], scaled by 0.125*log2(e)  (exp2 softmax)
// MODE 1: out K bf16 [b][h][n][64]
// MODE 2: out V^T bf16 [b][h][64][n]  (LDS transpose epilogue)
// MODE 3: out fp32 [m][n] + bias[n]
template<int MODE>
__global__ __launch_bounds__(256) void gemm_k(const u16* __restrict__ A,
                                              const u16* __restrict__ Bt,
                                              u16* __restrict__ outb,
                                              float* __restrict__ outf,
                                              const float* __restrict__ bias) {
  const int K = DIN;
  int m0 = blockIdx.x * 128;
  int n0 = blockIdx.y * 128;
  int tid = threadIdx.x;
  int lane = tid & 63, wid = tid >> 6;
  int wr = wid >> 1, wc = wid & 1;
  int g = lane >> 4, r = lane & 15;

  __shared__ __attribute__((aligned(16))) u16 lA[128*32];
  __shared__ __attribute__((aligned(16))) u16 lB[128*32];

  f32x4 acc[4][4];
#pragma unroll
  for (int i=0;i<4;i++)
#pragma unroll
    for (int j=0;j<4;j++) acc[i][j] = (f32x4){0.f,0.f,0.f,0.f};

  for (int k0 = 0; k0 < K; k0 += 32) {
#pragma unroll
    for (int i=0;i<2;i++) {
      int ch = wid*2 + i;            // 8 chunks of 1024B per tile
      int e = ch*512 + lane*8;       // element index within tile
      int row = e >> 5, col = e & 31;
      __builtin_amdgcn_global_load_lds(
        (GLOBAL_AS void*)(A + (size_t)(m0+row)*K + k0 + col),
        (LDS_AS void*)(&lA[ch*512]), 16, 0, 0);
      __builtin_amdgcn_global_load_lds(
        (GLOBAL_AS void*)(Bt + (size_t)(n0+row)*K + k0 + col),
        (LDS_AS void*)(&lB[ch*512]), 16, 0, 0);
    }
    __syncthreads();
    short8 af[4], bf[4];
#pragma unroll
    for (int f=0; f<4; f++) {
      af[f] = *(const short8*)&lA[(wr*64 + f*16 + r)*32 + g*8];
      bf[f] = *(const short8*)&lB[(wc*64 + f*16 + r)*32 + g*8];
    }
#pragma unroll
    for (int fr=0; fr<4; fr++)
#pragma unroll
      for (int fc=0; fc<4; fc++)
        acc[fr][fc] = __builtin_amdgcn_mfma_f32_16x16x32_bf16(af[fr], bf[fc], acc[fr][fc], 0, 0, 0);
    __syncthreads();
  }

  if constexpr (MODE == 0 || MODE == 1) {
#pragma unroll
    for (int fr=0; fr<4; fr++)
#pragma unroll
      for (int fc=0; fc<4; fc++)
#pragma unroll
        for (int v=0; v<4; v++) {
          int row = m0 + wr*64 + fr*16 + g*4 + v;
          int cc  = n0 + wc*64 + fc*16 + r;
          int b = row >> 11, nn = row & (NSEQ-1);
          float val = acc[fr][fc][v];
          if constexpr (MODE == 0) val *= 0.18033688f;   // 0.125 * log2(e)
          outb[(((size_t)b*NH + (cc>>6))*NSEQ + nn)*HD + (cc&63)] = f2bf(val);
        }
  } else if constexpr (MODE == 2) {
    __shared__ __attribute__((aligned(16))) u16 lC[128*129];
#pragma unroll
    for (int fr=0; fr<4; fr++)
#pragma unroll
      for (int fc=0; fc<4; fc++)
#pragma unroll
        for (int v=0; v<4; v++) {
          int ii = wr*64 + fr*16 + g*4 + v;
          int jj = wc*64 + fc*16 + r;
          lC[ii*129 + jj] = f2bf(acc[fr][fc][v]);
        }
    __syncthreads();
    int b = m0 >> 11;
#pragma unroll 1
    for (int rep=0; rep<64; rep++) {
      int flat = rep*256 + tid;      // 16384 elements
      int jj = flat >> 7, ii = flat & 127;
      int cc = n0 + jj;
      int nn = (m0 + ii) & (NSEQ-1);
      outb[(((size_t)b*NH + (cc>>6))*HD + (cc&63))*NSEQ + nn] = lC[ii*129 + jj];
    }
  } else {
#pragma unroll
    for (int fr=0; fr<4; fr++)
#pragma unroll
      for (int fc=0; fc<4; fc++)
#pragma unroll
        for (int v=0; v<4; v++) {
          int row = m0 + wr*64 + fr*16 + g*4 + v;
          int cc  = n0 + wc*64 + fc*16 + r;
          outf[(size_t)row*DOUT + cc] = acc[fr][fc][v] + bias[cc];
        }
  }
}

// ---------------- flash attention v5 ---------------------------------------
// Block = 4 waves = 2 pairs; pair p owns 32 q rows, and within a pair the two
// waves split each 64-kv tile into halves (ch=0: kv 0..31, ch=1: kv 32..63)
// so BOTH waves compute EVERY tile (no parity idling). Private (m,l,O) per
// wave, merged through LDS once per phase. Mirror chunk-pairing (chunk c then
// 31-c) keeps per-block work uniform (33 staged tiles).
// XCD pinning: 1-D grid; block i -> XCD i&7 (dispatch round-robin); bh =
// (i&7)*6 + (i>>3)/16 so each XCD serves 6 bh whose K+V (3MB) fit its 4MB L2.
// Pipeline: top-of-loop s_waitcnt vmcnt(0) + raw s_barrier -> the prefetch
// issued in iter t has the full iteration to land (latency hidden), one
// barrier per tile.
__global__ __launch_bounds__(256, 3) void attn5_k(const u16* __restrict__ Q,
                                                  const u16* __restrict__ Kg,
                                                  const u16* __restrict__ Vt,
                                                  u16* __restrict__ ctx) {
  int i = blockIdx.x;
  int xcd = i & 7, j = i >> 3;         // j in 0..95
  int bh = xcd * 6 + (j >> 4);         // 6 bh per XCD
  int cp = j & 15;                     // chunk-pair 0..15
  int lane = threadIdx.x & 63;
  int w = threadIdx.x >> 6;
  int p = w >> 1;                      // pair id (q sub-chunk)
  int ch = w & 1;                      // kv half within each tile
  int col = lane & 31;
  int hi = lane >> 5;
  int sw = (col & 7) << 4;             // read-side swizzle

  const u16* Qb = Q  + (size_t)bh * NSEQ * HD;
  const u16* Kb = Kg + (size_t)bh * NSEQ * HD;
  const u16* Vb = Vt + (size_t)bh * HD * NSEQ;

  __shared__ __attribute__((aligned(16))) char smem[2][16384];  // {K:0..8K, V:8K..16K} x dbuf

  // stage one 64-kv tile (K 8KB + V^T 8KB) cooperatively (4 waves)
  auto stage = [&](int buf, int k0) {
#pragma unroll
    for (int ii=0; ii<2; ii++) {
      int cb = (w*2+ii) * 1024;
      int d  = cb + lane*16;
      int row = d >> 7;
      int src = (d & 127) ^ ((row & 7) << 4);
      __builtin_amdgcn_global_load_lds(
        (GLOBAL_AS void*)((const char*)Kb + (size_t)(k0+row)*128 + src),
        (LDS_AS void*)(&smem[buf][cb]), 16, 0, 0);
      __builtin_amdgcn_global_load_lds(
        (GLOBAL_AS void*)((const char*)Vb + (size_t)row*(NSEQ*2) + (size_t)k0*2 + src),
        (LDS_AS void*)(&smem[buf][8192+cb]), 16, 0, 0);
    }
  };

#pragma unroll 1
  for (int ph = 0; ph < 2; ph++) {
    int chunk = ph ? (31 - cp) : cp;   // 64-row q chunk index (0..31)
    int nkt = chunk + 1;
    int qw0 = chunk*64 + p*32;
    int q = qw0 + col;

    short8 qf[4];
#pragma unroll
    for (int ksl = 0; ksl < 4; ksl++)
      qf[ksl] = *(const short8*)&Qb[(size_t)q * HD + ksl*16 + hi*8];

    f32x16 od[2];
#pragma unroll
    for (int z=0; z<16; z++) { od[0][z] = 0.f; od[1][z] = 0.f; }
    float m = -1e30f, l = 0.f;

    stage(0, 0);

#pragma unroll 1
    for (int t = 0; t < nkt; t++) {
      // top drain: stage(t) landed; all waves finished compute(t-1)
      asm volatile("s_waitcnt vmcnt(0)" ::: "memory");
      __builtin_amdgcn_s_barrier();
      asm volatile("" ::: "memory");

      if (t + 1 < nkt) stage((t+1) & 1, (t+1)*64);

      int k0c = t*64 + ch*32;          // this wave's kv-half base
      if (k0c <= qw0 + 31) {           // wave has live kv in this half
        const char* Kt = &smem[t & 1][0];
        const char* Vtile = &smem[t & 1][8192];
        // ---- QK^T (half-tile: 32 kv rows, K=64) ----
        f32x16 s;
#pragma unroll
        for (int z=0; z<16; z++) s[z] = 0.f;
#pragma unroll
        for (int ksl=0; ksl<4; ksl++) {
          short8 kf = *(const short8*)(Kt + (ch*32+col)*128 + ((ksl*32 + hi*16) ^ sw));
          s = __builtin_amdgcn_mfma_f32_32x32x16_bf16(kf, qf[ksl], s, 0, 0, 0);
        }
        if (k0c + 31 > qw0) {          // straddles the diagonal: mask
#pragma unroll
          for (int r=0; r<16; r++) {
            int kv = k0c + (r&3) + 8*(r>>2) + 4*hi;
            if (kv > q) s[r] = -1e30f;
          }
        }
        // ---- online softmax (per-lane q-row; hi-pair shares via shfl32) ----
        float u8[8];
#pragma unroll
        for (int r=0; r<8; r++) u8[r] = fmaxf(s[r], s[r+8]);
#pragma unroll
        for (int r=0; r<4; r++) u8[r] = fmaxf(u8[r], u8[r+4]);
        float pm = fmaxf(fmaxf(u8[0], u8[1]), fmaxf(u8[2], u8[3]));
        pm = fmaxf(pm, __shfl_xor(pm, 32));
        if (!__all(pm <= m + 8.0f)) {  // defer-rescale (log2 domain)
          float mnew = fmaxf(m, pm);
          float sc = __builtin_amdgcn_exp2f(m - mnew);
          l *= sc;
#pragma unroll
          for (int z=0; z<16; z++) { od[0][z] *= sc; od[1][z] *= sc; }
          m = mnew;
        }
        float rs = 0.f;
        uint32_t a[8];
#pragma unroll
        for (int ww=0; ww<8; ww++) {
          float p0 = __builtin_amdgcn_exp2f(s[2*ww]   - m);
          float p1 = __builtin_amdgcn_exp2f(s[2*ww+1] - m);
          rs += p0 + p1;
          a[ww] = pack2b(p0, p1);
        }
        rs += __shfl_xor(rs, 32);
        l += rs;

        // ---- PV: O^T += Vt_half * P^T_half (K=32) ----
        uint32_t b[8];
#pragma unroll
        for (int ww=0; ww<8; ww++) b[ww] = (uint32_t)__shfl_xor((int)a[ww], 32);
        union { uint32_t wdat[4]; short8 s8; } u0, u1;
        u0.wdat[0] = hi ? b[2]   : a[0];
        u0.wdat[1] = hi ? b[3]   : a[1];
        u0.wdat[2] = hi ? a[2]   : b[0];
        u0.wdat[3] = hi ? a[3]   : b[1];
        u1.wdat[0] = hi ? b[6]   : a[4];
        u1.wdat[1] = hi ? b[7]   : a[5];
        u1.wdat[2] = hi ? a[6]   : b[4];
        u1.wdat[3] = hi ? a[7]   : b[5];
#pragma unroll
        for (int dc=0; dc<2; dc++) {
          short8 vf0 = *(const short8*)(Vtile + (dc*32+col)*128 + ((ch*64 + hi*16) ^ sw));
          od[dc] = __builtin_amdgcn_mfma_f32_32x32x16_bf16(vf0, u0.s8, od[dc], 0, 0, 0);
          short8 vf1 = *(const short8*)(Vtile + (dc*32+col)*128 + ((ch*64 + 32 + hi*16) ^ sw));
          od[dc] = __builtin_amdgcn_mfma_f32_32x32x16_bf16(vf1, u1.s8, od[dc], 0, 0, 0);
        }
      }
    }
    __syncthreads();   // all compute done before merge overwrites smem

    // ---- pair merge through LDS (staging region reused) ----
    float* mg = (float*)&smem[0][0] + p * (34*64);
    if (ch) {
#pragma unroll
      for (int dc=0; dc<2; dc++)
#pragma unroll
        for (int jj=0; jj<16; jj++) mg[(dc*16+jj)*64 + lane] = od[dc][jj];
      mg[32*64 + lane] = m;
      mg[33*64 + lane] = l;
    }
    __syncthreads();
    if (!ch) {
      float mB = mg[32*64 + lane], lB = mg[33*64 + lane];
      float mM = fmaxf(m, mB);
      float ea = __builtin_amdgcn_exp2f(m - mM);
      float eb = __builtin_amdgcn_exp2f(mB - mM);
      float inv = 1.0f / (l*ea + lB*eb);
      float fa = ea * inv, fb = eb * inv;
      int b = bh / NH, h = bh % NH;
      u16* cp_ = ctx + ((size_t)b * NSEQ + q) * DOUT + h * HD;
#pragma unroll
      for (int dc=0; dc<2; dc++)
#pragma unroll
        for (int t4=0; t4<4; t4++) {
          int d0 = dc*32 + t4*8 + hi*4;
          float v0 = od[dc][t4*4+0]*fa + mg[(dc*16+t4*4+0)*64 + lane]*fb;
          float v1 = od[dc][t4*4+1]*fa + mg[(dc*16+t4*4+1)*64 + lane]*fb;
          float v2 = od[dc][t4*4+2]*fa + mg[(dc*16+t4*4+2)*64 + lane]*fb;
          float v3 = od[dc][t4*4+3]*fa + mg[(dc*16+t4*4+3)*64 + lane]*fb;
          *(uint32_t*)(cp_ + d0)     = pack2b(v0, v1);
          *(uint32_t*)(cp_ + d0 + 2) = pack2b(v2, v3);
        }
    }
    __syncthreads();   // protect merge region before next phase's staging
  }
}

// ---------------------------------------------------------------------------
extern "C" void kernel_launch(void* const* d_in, const int* in_sizes, int n_in,
                              void* d_out, int out_size, void* d_ws, size_t ws_size,
                              hipStream_t stream) {
  const float* x   = (const float*)d_in[0];
  const float* Wq  = (const float*)d_in[1];
  const float* Wk  = (const float*)d_in[2];
  const float* Wv  = (const float*)d_in[3];
  const float* Wo  = (const float*)d_in[4];
  const float* bo  = (const float*)d_in[5];
  float* out = (float*)d_out;

  u16* ws  = (u16*)d_ws;
  u16* xb  = ws;                         // [8192][768]
  u16* WqT = xb  + (size_t)MROWS*DIN;    // [768][768] transposed
  u16* WkT = WqT + (size_t)DIN*DOUT;
  u16* WvT = WkT + (size_t)DIN*DOUT;
  u16* WoT = WvT + (size_t)DIN*DOUT;
  u16* Qg  = WoT + (size_t)DIN*DOUT;     // [b][h][n][64]  (pre-scaled)
  u16* Kg  = Qg  + (size_t)MROWS*DOUT;   // [b][h][n][64]
  u16* Vt  = Kg  + (size_t)MROWS*DOUT;   // [b][h][64][n]
  u16* ctx = Vt  + (size_t)MROWS*DOUT;   // [b][n][768]

  convert_k<<<2048, 256, 0, stream>>>(x, Wq, Wk, Wv, Wo, xb, WqT, WkT, WvT, WoT);

  dim3 gg(MROWS/128, DOUT/128);
  gemm_k<0><<<gg, 256, 0, stream>>>(xb, WqT, Qg, nullptr, nullptr);
  gemm_k<1><<<gg, 256, 0, stream>>>(xb, WkT, Kg, nullptr, nullptr);
  gemm_k<2><<<gg, 256, 0, stream>>>(xb, WvT, Vt, nullptr, nullptr);

  attn5_k<<<768, 256, 0, stream>>>(Qg, Kg, Vt, ctx);

  gemm_k<3><<<gg, 256, 0, stream>>>(ctx, WoT, nullptr, out, bo);
}